// Round 3
// baseline (792.267 us; speedup 1.0000x reference)
//
#include <hip/hip_runtime.h>
#include <hip/hip_bf16.h>
#include <cstdint>
#include <cstddef>

// GCN: 6 layers (128->64, then 5x 64->64), gcn_norm with self-loops,
// sum+max pooling over 64 graphs, 3-layer MLP head.
// Strategy: build CSR (by dst) once per call. Norm is factored:
//   h[v] = relu(b + dinv[v] * (t'[v] + sum_e t'[src_e])),  t'[r] = dinv[r]*(x[r]@W)
// so the CSR carries ONLY src indices (4B/edge scatter, no csr_w).

#define FEAT 64

// ---------------- setup kernels ----------------

__global__ __launch_bounds__(256) void init_kernel(int* deg, int* cursor,
    float* gsum, unsigned int* gmax, int n) {
  int i = blockIdx.x * 256 + threadIdx.x;
  if (i < n) { deg[i] = 0; cursor[i] = 0; }
  if (i < 64 * FEAT) { gsum[i] = 0.f; gmax[i] = 0xFF800000u; }  // -inf bits
}

__global__ __launch_bounds__(256) void hist_kernel(const int* __restrict__ dst,
    int* __restrict__ deg, int e) {
  int i = blockIdx.x * 256 + threadIdx.x;
  if (i < e) atomicAdd(&deg[dst[i]], 1);
}

__global__ __launch_bounds__(256) void dinv_kernel(const int* __restrict__ deg,
    float* __restrict__ dinv, int n) {
  int i = blockIdx.x * 256 + threadIdx.x;
  if (i < n) dinv[i] = rsqrtf((float)(deg[i] + 1));  // +1 self-loop; always >=1
}

__global__ __launch_bounds__(256) void scan1_kernel(const int* __restrict__ deg,
    int* __restrict__ offs, int* __restrict__ bsums, int n) {
  __shared__ int buf[256];
  int t = threadIdx.x;
  int i = blockIdx.x * 256 + t;
  int v = (i < n) ? deg[i] : 0;
  buf[t] = v;
  __syncthreads();
  for (int off = 1; off < 256; off <<= 1) {
    int add = (t >= off) ? buf[t - off] : 0;
    __syncthreads();
    buf[t] += add;
    __syncthreads();
  }
  if (i < n) offs[i] = buf[t] - v;           // exclusive within block
  if (t == 255) bsums[blockIdx.x] = buf[255];
}

__global__ __launch_bounds__(512) void scan2_kernel(int* bs, int nb) {
  __shared__ int buf[512];
  int t = threadIdx.x;
  int v = (t < nb) ? bs[t] : 0;
  buf[t] = v;
  __syncthreads();
  for (int off = 1; off < 512; off <<= 1) {
    int add = (t >= off) ? buf[t - off] : 0;
    __syncthreads();
    buf[t] += add;
    __syncthreads();
  }
  if (t < nb) bs[t] = buf[t] - v;            // exclusive block offsets
}

__global__ __launch_bounds__(256) void scan3_kernel(int* __restrict__ offs,
    const int* __restrict__ bs, int n) {
  int i = blockIdx.x * 256 + threadIdx.x;
  if (i < n) offs[i] += bs[blockIdx.x];
}

__global__ __launch_bounds__(256) void fill_kernel(const int* __restrict__ src,
    const int* __restrict__ dst, const int* __restrict__ offs,
    int* __restrict__ cursor, int* __restrict__ csr_src, int e) {
  int i = blockIdx.x * 256 + threadIdx.x;
  if (i >= e) return;
  int d = dst[i], s = src[i];
  int pos = offs[d] + atomicAdd(&cursor[d], 1);
  csr_src[pos] = s;
}

// ---------------- GEMM: out[N,64] = dinv[r] * (in[N,K] @ W[K,64]) ------
// One block per 64-row tile. W[:,lane] held in VGPRs (full unroll).
// Input tile staged in LDS with coalesced float4 loads; compute reads it
// via wave-uniform broadcast b128 (conflict-free). 4 rows in flight.
template <int K>
__global__ __launch_bounds__(256, 2) void gemm_kernel(
    const float* __restrict__ in, const float* __restrict__ W,
    const float* __restrict__ dinv, float* __restrict__ out, int n) {
  __shared__ float in_lds[64 * K];
  const int lane = threadIdx.x & 63;
  const int wid = threadIdx.x >> 6;

  float wreg[K];
#pragma unroll
  for (int k = 0; k < K; ++k) wreg[k] = W[k * 64 + lane];

  const int ntiles = n >> 6;
  for (int tile = blockIdx.x; tile < ntiles; tile += gridDim.x) {
    const float* tin = in + (size_t)tile * 64 * K;
    __syncthreads();  // previous tile's compute done before overwrite
#pragma unroll
    for (int i = threadIdx.x; i < 16 * K; i += 256)
      *(float4*)&in_lds[i * 4] = *(const float4*)&tin[i * 4];
    __syncthreads();

    float* tout = out + (size_t)tile * 64 * 64;
    const float* dvp = dinv + tile * 64;
#pragma unroll
    for (int g = 0; g < 4; ++g) {
      const int r0 = wid * 16 + g * 4;
      float a0 = 0.f, a1 = 0.f, a2 = 0.f, a3 = 0.f;
#pragma unroll
      for (int k = 0; k < K; k += 4) {
        float4 x0 = *(const float4*)&in_lds[(r0 + 0) * K + k];
        float4 x1 = *(const float4*)&in_lds[(r0 + 1) * K + k];
        float4 x2 = *(const float4*)&in_lds[(r0 + 2) * K + k];
        float4 x3 = *(const float4*)&in_lds[(r0 + 3) * K + k];
        a0 = fmaf(x0.x, wreg[k + 0], a0); a0 = fmaf(x0.y, wreg[k + 1], a0);
        a0 = fmaf(x0.z, wreg[k + 2], a0); a0 = fmaf(x0.w, wreg[k + 3], a0);
        a1 = fmaf(x1.x, wreg[k + 0], a1); a1 = fmaf(x1.y, wreg[k + 1], a1);
        a1 = fmaf(x1.z, wreg[k + 2], a1); a1 = fmaf(x1.w, wreg[k + 3], a1);
        a2 = fmaf(x2.x, wreg[k + 0], a2); a2 = fmaf(x2.y, wreg[k + 1], a2);
        a2 = fmaf(x2.z, wreg[k + 2], a2); a2 = fmaf(x2.w, wreg[k + 3], a2);
        a3 = fmaf(x3.x, wreg[k + 0], a3); a3 = fmaf(x3.y, wreg[k + 1], a3);
        a3 = fmaf(x3.z, wreg[k + 2], a3); a3 = fmaf(x3.w, wreg[k + 3], a3);
      }
      tout[(r0 + 0) * 64 + lane] = a0 * dvp[r0 + 0];
      tout[(r0 + 1) * 64 + lane] = a1 * dvp[r0 + 1];
      tout[(r0 + 2) * 64 + lane] = a2 * dvp[r0 + 2];
      tout[(r0 + 3) * 64 + lane] = a3 * dvp[r0 + 3];
    }
  }
}

// ---------------- AGG: h[v] = relu?( b + dinv[v] * (t'[v] + sum_e t'[src_e]) )
// One wave per node; lane = feature; 256B coalesced gathers; no per-edge weight.
__global__ __launch_bounds__(256) void agg_kernel(const float* __restrict__ t,
    const int* __restrict__ csr_src, const int* __restrict__ offs,
    const int* __restrict__ cnt, const float* __restrict__ dinv,
    const float* __restrict__ bias, float* __restrict__ h, int n, int relu) {
  int wave = (blockIdx.x * 256 + threadIdx.x) >> 6;
  int lane = threadIdx.x & 63;
  if (wave >= n) return;
  int v = wave;
  float acc = t[(size_t)v * 64 + lane];   // self-loop term (already dinv-scaled)
  int j = offs[v];
  int end = j + cnt[v];
  for (; j + 3 < end; j += 4) {
    int s0 = csr_src[j + 0], s1 = csr_src[j + 1];
    int s2 = csr_src[j + 2], s3 = csr_src[j + 3];
    float t0 = t[(size_t)s0 * 64 + lane];
    float t1 = t[(size_t)s1 * 64 + lane];
    float t2 = t[(size_t)s2 * 64 + lane];
    float t3 = t[(size_t)s3 * 64 + lane];
    acc += t0 + t1 + t2 + t3;
  }
  for (; j < end; ++j) {
    int s = csr_src[j];
    acc += t[(size_t)s * 64 + lane];
  }
  acc = fmaf(dinv[v], acc, bias[lane]);
  if (relu) acc = fmaxf(acc, 0.f);
  h[(size_t)v * 64 + lane] = acc;
}

// ---------------- pooling: per-graph sum + max ----------------

__device__ inline void atomic_max_float(float* addr, float val) {
  if (val >= 0.f)
    atomicMax((int*)addr, __float_as_int(val));
  else
    atomicMin((unsigned int*)addr, (unsigned int)__float_as_int(val));
}

#define POOL_CHUNK 128

__global__ __launch_bounds__(256) void pool_kernel(const float* __restrict__ h,
    const int* __restrict__ batch, float* __restrict__ gsum,
    float* __restrict__ gmax, int n) {
  int wave = (blockIdx.x * 256 + threadIdx.x) >> 6;
  int lane = threadIdx.x & 63;
  int start = wave * POOL_CHUNK;
  if (start >= n) return;
  int end = min(start + POOL_CHUNK, n);
  float s = 0.f, m = -INFINITY;
  int cur = batch[start];
  for (int v = start; v < end; ++v) {
    int g = batch[v];
    if (g != cur) {
      atomicAdd(&gsum[cur * 64 + lane], s);
      atomic_max_float(&gmax[cur * 64 + lane], m);
      s = 0.f; m = -INFINITY; cur = g;
    }
    float x = h[(size_t)v * 64 + lane];
    s += x;
    m = fmaxf(m, x);
  }
  atomicAdd(&gsum[cur * 64 + lane], s);
  atomic_max_float(&gmax[cur * 64 + lane], m);
}

// ---------------- MLP head (single block) ----------------

__global__ __launch_bounds__(256) void mlp_kernel(const float* __restrict__ gsum,
    const float* __restrict__ gmax, const float* __restrict__ w1,
    const float* __restrict__ b1, const float* __restrict__ w2,
    const float* __restrict__ b2, const float* __restrict__ w3,
    const float* __restrict__ b3, float* __restrict__ out) {
  __shared__ float smem[64 * 128 + 64 * 64];  // 48KB: gg then z1; z2 overlays gg
  float* gg = smem;
  float* z1 = smem + 64 * 128;
  int t = threadIdx.x;
  for (int i = t; i < 64 * 128; i += 256) {
    int g = i >> 7, f = i & 127;
    gg[i] = (f < 64) ? gsum[g * 64 + f] : gmax[g * 64 + (f - 64)];
  }
  __syncthreads();
  for (int i = t; i < 64 * 64; i += 256) {
    int g = i >> 6, j = i & 63;
    float acc = b1[j];
    for (int f = 0; f < 128; ++f) acc = fmaf(gg[(g << 7) + f], w1[f * 64 + j], acc);
    z1[i] = fmaxf(acc, 0.f);
  }
  __syncthreads();
  float* z2 = smem;  // gg region is dead now
  for (int i = t; i < 64 * 64; i += 256) {
    int g = i >> 6, j = i & 63;
    float acc = b2[j];
    for (int f = 0; f < 64; ++f) acc = fmaf(z1[(g << 6) + f], w2[f * 64 + j], acc);
    z2[i] = fmaxf(acc, 0.f);
  }
  __syncthreads();
  if (t < 64) {
    float acc = b3[0];
    for (int j = 0; j < 64; ++j) acc = fmaf(z2[(t << 6) + j], w3[j], acc);
    out[t] = acc;
  }
}

// ---------------- launch ----------------

extern "C" void kernel_launch(void* const* d_in, const int* in_sizes, int n_in,
                              void* d_out, int out_size, void* d_ws, size_t ws_size,
                              hipStream_t stream) {
  const float* x      = (const float*)d_in[0];
  const int*   eidx   = (const int*)d_in[1];
  const int*   batch  = (const int*)d_in[2];
  const float* W_in   = (const float*)d_in[3];
  const float* b_in   = (const float*)d_in[4];
  const float* W_hid  = (const float*)d_in[5];
  const float* b_hid  = (const float*)d_in[6];
  const float* lin1_w = (const float*)d_in[7];
  const float* lin1_b = (const float*)d_in[8];
  const float* lin2_w = (const float*)d_in[9];
  const float* lin2_b = (const float*)d_in[10];
  const float* lin3_w = (const float*)d_in[11];
  const float* lin3_b = (const float*)d_in[12];
  float* out = (float*)d_out;

  const int N = in_sizes[2];            // 80000
  const int E = in_sizes[1] / 2;        // 1280000
  const int CIN = in_sizes[0] / N;      // 128
  const int n_hid = in_sizes[5] / (64 * 64);  // 5

  const int* src = eidx;
  const int* dst = eidx + E;

  // workspace layout (256B-aligned slabs)
  char* ws = (char*)d_ws;
  size_t off = 0;
  auto alloc = [&](size_t bytes) {
    size_t o = off;
    off = (off + bytes + 255) & ~(size_t)255;
    return o;
  };
  int*   deg     = (int*)(ws + alloc((size_t)N * 4));
  int*   cursor  = (int*)(ws + alloc((size_t)N * 4));
  float* dinv    = (float*)(ws + alloc((size_t)N * 4));
  int*   offs    = (int*)(ws + alloc((size_t)N * 4));
  int*   bsums   = (int*)(ws + alloc(1024 * 4));
  int*   csr_src = (int*)(ws + alloc((size_t)E * 4));
  float* tbuf    = (float*)(ws + alloc((size_t)N * 64 * 4));
  float* hbuf    = (float*)(ws + alloc((size_t)N * 64 * 4));
  float* gsum    = (float*)(ws + alloc(64 * 64 * 4));
  float* gmax    = (float*)(ws + alloc(64 * 64 * 4));
  (void)ws_size; (void)n_in; (void)out_size; (void)CIN;

  const int nbN = (N + 255) / 256;   // 313
  const int nbE = (E + 255) / 256;

  init_kernel<<<nbN, 256, 0, stream>>>(deg, cursor, gsum, (unsigned int*)gmax, N);
  hist_kernel<<<nbE, 256, 0, stream>>>(dst, deg, E);
  dinv_kernel<<<nbN, 256, 0, stream>>>(deg, dinv, N);
  scan1_kernel<<<nbN, 256, 0, stream>>>(deg, offs, bsums, N);
  scan2_kernel<<<1, 512, 0, stream>>>(bsums, nbN);
  scan3_kernel<<<nbN, 256, 0, stream>>>(offs, bsums, N);
  fill_kernel<<<nbE, 256, 0, stream>>>(src, dst, offs, cursor, csr_src, E);

  const int ntiles = N >> 6;                    // 1250 (N % 64 == 0)
  const int agg_blocks = (N * 64 + 255) / 256;  // one wave per node

  // layer 0: 128 -> 64, ReLU
  gemm_kernel<128><<<ntiles, 256, 0, stream>>>(x, W_in, dinv, tbuf, N);
  agg_kernel<<<agg_blocks, 256, 0, stream>>>(tbuf, csr_src, offs, deg,
                                             dinv, b_in, hbuf, N, 1);
  // hidden layers: 64 -> 64, ReLU on all but last
  for (int i = 0; i < n_hid; ++i) {
    gemm_kernel<64><<<ntiles, 256, 0, stream>>>(hbuf, W_hid + (size_t)i * 64 * 64,
                                                dinv, tbuf, N);
    agg_kernel<<<agg_blocks, 256, 0, stream>>>(tbuf, csr_src, offs, deg,
                                               dinv, b_hid + (size_t)i * 64, hbuf, N,
                                               (i != n_hid - 1) ? 1 : 0);
  }

  const int pool_waves = (N + POOL_CHUNK - 1) / POOL_CHUNK;
  const int pool_blocks = (pool_waves * 64 + 255) / 256;
  pool_kernel<<<pool_blocks, 256, 0, stream>>>(hbuf, batch, gsum, gmax, N);

  mlp_kernel<<<1, 256, 0, stream>>>(gsum, gmax, lin1_w, lin1_b, lin2_w, lin2_b,
                                    lin3_w, lin3_b, out);
}

// Round 4
// 730.758 us; speedup vs baseline: 1.0842x; 1.0842x over previous
//
#include <hip/hip_runtime.h>
#include <hip/hip_bf16.h>
#include <cstdint>
#include <cstddef>

// GCN: 6 layers (128->64, then 5x 64->64), gcn_norm with self-loops,
// sum+max pooling over 64 graphs, 3-layer MLP head.
// Norm factored: h[v] = relu(b + dinv[v]*(t'[v] + sum_e t'[src_e])),
//   t'[r] = dinv[r]*(x[r]@W)  stored as bf16 (halves gather bytes).
// CSR built with XCD-sliced hist/fill: blockIdx%8 = XCD; each slice's
// deg/cursor/CSR region stays in its own L2 so scattered writes coalesce.

#define FEAT 64

static __device__ inline unsigned short f2bf(float f) {
  unsigned u = __float_as_uint(f);
  unsigned r = (u + 0x7FFF + ((u >> 16) & 1)) >> 16;  // round-to-nearest-even
  return (unsigned short)r;
}
static __device__ inline float bf2f(unsigned short u) {
  return __uint_as_float(((unsigned)u) << 16);
}

// ---------------- setup kernels ----------------

__global__ __launch_bounds__(256) void init_kernel(int* deg, int* cursor,
    float* gsum, unsigned int* gmax, int n) {
  int i = blockIdx.x * 256 + threadIdx.x;
  if (i < n) { deg[i] = 0; cursor[i] = 0; }
  if (i < 64 * FEAT) { gsum[i] = 0.f; gmax[i] = 0xFF800000u; }  // -inf bits
}

// XCD-sliced histogram: slice s = blockIdx%8 owns dst in [s*n/8,(s+1)*n/8).
__global__ __launch_bounds__(256) void hist_kernel(const int* __restrict__ dst,
    int* __restrict__ deg, int e, int n) {
  const int slice = blockIdx.x & 7;
  const int lo = slice * (n >> 3);
  const int hi = lo + (n >> 3);
  const int nb = gridDim.x >> 3;
  const int bid = blockIdx.x >> 3;
  for (int i = bid * 256 + threadIdx.x; i < e; i += nb * 256) {
    int d = dst[i];
    if (d >= lo && d < hi) atomicAdd(&deg[d], 1);
  }
}

__global__ __launch_bounds__(256) void dinv_kernel(const int* __restrict__ deg,
    float* __restrict__ dinv, int n) {
  int i = blockIdx.x * 256 + threadIdx.x;
  if (i < n) dinv[i] = rsqrtf((float)(deg[i] + 1));  // +1 self-loop; always >=1
}

__global__ __launch_bounds__(256) void scan1_kernel(const int* __restrict__ deg,
    int* __restrict__ offs, int* __restrict__ bsums, int n) {
  __shared__ int buf[256];
  int t = threadIdx.x;
  int i = blockIdx.x * 256 + t;
  int v = (i < n) ? deg[i] : 0;
  buf[t] = v;
  __syncthreads();
  for (int off = 1; off < 256; off <<= 1) {
    int add = (t >= off) ? buf[t - off] : 0;
    __syncthreads();
    buf[t] += add;
    __syncthreads();
  }
  if (i < n) offs[i] = buf[t] - v;           // exclusive within block
  if (t == 255) bsums[blockIdx.x] = buf[255];
}

__global__ __launch_bounds__(512) void scan2_kernel(int* bs, int nb) {
  __shared__ int buf[512];
  int t = threadIdx.x;
  int v = (t < nb) ? bs[t] : 0;
  buf[t] = v;
  __syncthreads();
  for (int off = 1; off < 512; off <<= 1) {
    int add = (t >= off) ? buf[t - off] : 0;
    __syncthreads();
    buf[t] += add;
    __syncthreads();
  }
  if (t < nb) bs[t] = buf[t] - v;            // exclusive block offsets
}

__global__ __launch_bounds__(256) void scan3_kernel(int* __restrict__ offs,
    const int* __restrict__ bs, int n) {
  int i = blockIdx.x * 256 + threadIdx.x;
  if (i < n) offs[i] += bs[blockIdx.x];
}

// XCD-sliced CSR fill: slice's cursor + CSR region (contiguous, ~640KB)
// stay L2-local so 4B scatters coalesce before writeback.
__global__ __launch_bounds__(256) void fill_kernel(const int* __restrict__ src,
    const int* __restrict__ dst, const int* __restrict__ offs,
    int* __restrict__ cursor, int* __restrict__ csr_src, int e, int n) {
  const int slice = blockIdx.x & 7;
  const int lo = slice * (n >> 3);
  const int hi = lo + (n >> 3);
  const int nb = gridDim.x >> 3;
  const int bid = blockIdx.x >> 3;
  for (int i = bid * 256 + threadIdx.x; i < e; i += nb * 256) {
    int d = dst[i];
    if (d >= lo && d < hi) {
      int pos = offs[d] + atomicAdd(&cursor[d], 1);
      csr_src[pos] = src[i];
    }
  }
}

// ---------------- GEMM: tg[N,64](bf16) = dinv[r] * (in[N,K] @ W[K,64]) ----
// One block per 64-row tile. W[:,lane] in VGPRs; input tile staged in LDS
// via coalesced float4; compute reads LDS with uniform broadcast b128.
template <int K>
__global__ __launch_bounds__(256, 2) void gemm_kernel(
    const float* __restrict__ in, const float* __restrict__ W,
    const float* __restrict__ dinv, unsigned short* __restrict__ tg, int n) {
  __shared__ float in_lds[64 * K];
  const int lane = threadIdx.x & 63;
  const int wid = threadIdx.x >> 6;

  float wreg[K];
#pragma unroll
  for (int k = 0; k < K; ++k) wreg[k] = W[k * 64 + lane];

  const int ntiles = n >> 6;
  for (int tile = blockIdx.x; tile < ntiles; tile += gridDim.x) {
    const float* tin = in + (size_t)tile * 64 * K;
    __syncthreads();  // previous tile's compute done before overwrite
#pragma unroll
    for (int i = threadIdx.x; i < 16 * K; i += 256)
      *(float4*)&in_lds[i * 4] = *(const float4*)&tin[i * 4];
    __syncthreads();

    unsigned short* tout = tg + (size_t)tile * 64 * 64;
    const float* dvp = dinv + tile * 64;
#pragma unroll
    for (int g = 0; g < 4; ++g) {
      const int r0 = wid * 16 + g * 4;
      float a0 = 0.f, a1 = 0.f, a2 = 0.f, a3 = 0.f;
#pragma unroll
      for (int k = 0; k < K; k += 4) {
        float4 x0 = *(const float4*)&in_lds[(r0 + 0) * K + k];
        float4 x1 = *(const float4*)&in_lds[(r0 + 1) * K + k];
        float4 x2 = *(const float4*)&in_lds[(r0 + 2) * K + k];
        float4 x3 = *(const float4*)&in_lds[(r0 + 3) * K + k];
        a0 = fmaf(x0.x, wreg[k + 0], a0); a0 = fmaf(x0.y, wreg[k + 1], a0);
        a0 = fmaf(x0.z, wreg[k + 2], a0); a0 = fmaf(x0.w, wreg[k + 3], a0);
        a1 = fmaf(x1.x, wreg[k + 0], a1); a1 = fmaf(x1.y, wreg[k + 1], a1);
        a1 = fmaf(x1.z, wreg[k + 2], a1); a1 = fmaf(x1.w, wreg[k + 3], a1);
        a2 = fmaf(x2.x, wreg[k + 0], a2); a2 = fmaf(x2.y, wreg[k + 1], a2);
        a2 = fmaf(x2.z, wreg[k + 2], a2); a2 = fmaf(x2.w, wreg[k + 3], a2);
        a3 = fmaf(x3.x, wreg[k + 0], a3); a3 = fmaf(x3.y, wreg[k + 1], a3);
        a3 = fmaf(x3.z, wreg[k + 2], a3); a3 = fmaf(x3.w, wreg[k + 3], a3);
      }
      tout[(r0 + 0) * 64 + lane] = f2bf(a0 * dvp[r0 + 0]);
      tout[(r0 + 1) * 64 + lane] = f2bf(a1 * dvp[r0 + 1]);
      tout[(r0 + 2) * 64 + lane] = f2bf(a2 * dvp[r0 + 2]);
      tout[(r0 + 3) * 64 + lane] = f2bf(a3 * dvp[r0 + 3]);
    }
  }
}

// ---------------- AGG: h[v] = relu?( b + dinv[v] * (t'[v] + sum_e t'[src_e]) )
// One wave per node; lane = feature; 128B coalesced bf16 gathers.
__global__ __launch_bounds__(256) void agg_kernel(
    const unsigned short* __restrict__ tg, const int* __restrict__ csr_src,
    const int* __restrict__ offs, const int* __restrict__ cnt,
    const float* __restrict__ dinv, const float* __restrict__ bias,
    float* __restrict__ h, int n, int relu) {
  int wave = (blockIdx.x * 256 + threadIdx.x) >> 6;
  int lane = threadIdx.x & 63;
  if (wave >= n) return;
  int v = wave;
  float acc = bf2f(tg[(size_t)v * 64 + lane]);  // self term (dinv-scaled)
  int j = offs[v];
  int end = j + cnt[v];
  for (; j + 3 < end; j += 4) {
    int s0 = csr_src[j + 0], s1 = csr_src[j + 1];
    int s2 = csr_src[j + 2], s3 = csr_src[j + 3];
    unsigned short u0 = tg[(size_t)s0 * 64 + lane];
    unsigned short u1 = tg[(size_t)s1 * 64 + lane];
    unsigned short u2 = tg[(size_t)s2 * 64 + lane];
    unsigned short u3 = tg[(size_t)s3 * 64 + lane];
    acc += bf2f(u0) + bf2f(u1) + bf2f(u2) + bf2f(u3);
  }
  for (; j < end; ++j) {
    int s = csr_src[j];
    acc += bf2f(tg[(size_t)s * 64 + lane]);
  }
  acc = fmaf(dinv[v], acc, bias[lane]);
  if (relu) acc = fmaxf(acc, 0.f);
  h[(size_t)v * 64 + lane] = acc;
}

// ---------------- pooling: per-graph sum + max ----------------

__device__ inline void atomic_max_float(float* addr, float val) {
  if (val >= 0.f)
    atomicMax((int*)addr, __float_as_int(val));
  else
    atomicMin((unsigned int*)addr, (unsigned int)__float_as_int(val));
}

#define POOL_CHUNK 128

__global__ __launch_bounds__(256) void pool_kernel(const float* __restrict__ h,
    const int* __restrict__ batch, float* __restrict__ gsum,
    float* __restrict__ gmax, int n) {
  int wave = (blockIdx.x * 256 + threadIdx.x) >> 6;
  int lane = threadIdx.x & 63;
  int start = wave * POOL_CHUNK;
  if (start >= n) return;
  int end = min(start + POOL_CHUNK, n);
  float s = 0.f, m = -INFINITY;
  int cur = batch[start];
  for (int v = start; v < end; ++v) {
    int g = batch[v];
    if (g != cur) {
      atomicAdd(&gsum[cur * 64 + lane], s);
      atomic_max_float(&gmax[cur * 64 + lane], m);
      s = 0.f; m = -INFINITY; cur = g;
    }
    float x = h[(size_t)v * 64 + lane];
    s += x;
    m = fmaxf(m, x);
  }
  atomicAdd(&gsum[cur * 64 + lane], s);
  atomic_max_float(&gmax[cur * 64 + lane], m);
}

// ---------------- MLP head (single block) ----------------

__global__ __launch_bounds__(256) void mlp_kernel(const float* __restrict__ gsum,
    const float* __restrict__ gmax, const float* __restrict__ w1,
    const float* __restrict__ b1, const float* __restrict__ w2,
    const float* __restrict__ b2, const float* __restrict__ w3,
    const float* __restrict__ b3, float* __restrict__ out) {
  __shared__ float smem[64 * 128 + 64 * 64];  // 48KB: gg then z1; z2 overlays gg
  float* gg = smem;
  float* z1 = smem + 64 * 128;
  int t = threadIdx.x;
  for (int i = t; i < 64 * 128; i += 256) {
    int g = i >> 7, f = i & 127;
    gg[i] = (f < 64) ? gsum[g * 64 + f] : gmax[g * 64 + (f - 64)];
  }
  __syncthreads();
  for (int i = t; i < 64 * 64; i += 256) {
    int g = i >> 6, j = i & 63;
    float acc = b1[j];
    for (int f = 0; f < 128; ++f) acc = fmaf(gg[(g << 7) + f], w1[f * 64 + j], acc);
    z1[i] = fmaxf(acc, 0.f);
  }
  __syncthreads();
  float* z2 = smem;  // gg region is dead now
  for (int i = t; i < 64 * 64; i += 256) {
    int g = i >> 6, j = i & 63;
    float acc = b2[j];
    for (int f = 0; f < 64; ++f) acc = fmaf(z1[(g << 6) + f], w2[f * 64 + j], acc);
    z2[i] = fmaxf(acc, 0.f);
  }
  __syncthreads();
  if (t < 64) {
    float acc = b3[0];
    for (int j = 0; j < 64; ++j) acc = fmaf(z2[(t << 6) + j], w3[j], acc);
    out[t] = acc;
  }
}

// ---------------- launch ----------------

extern "C" void kernel_launch(void* const* d_in, const int* in_sizes, int n_in,
                              void* d_out, int out_size, void* d_ws, size_t ws_size,
                              hipStream_t stream) {
  const float* x      = (const float*)d_in[0];
  const int*   eidx   = (const int*)d_in[1];
  const int*   batch  = (const int*)d_in[2];
  const float* W_in   = (const float*)d_in[3];
  const float* b_in   = (const float*)d_in[4];
  const float* W_hid  = (const float*)d_in[5];
  const float* b_hid  = (const float*)d_in[6];
  const float* lin1_w = (const float*)d_in[7];
  const float* lin1_b = (const float*)d_in[8];
  const float* lin2_w = (const float*)d_in[9];
  const float* lin2_b = (const float*)d_in[10];
  const float* lin3_w = (const float*)d_in[11];
  const float* lin3_b = (const float*)d_in[12];
  float* out = (float*)d_out;

  const int N = in_sizes[2];            // 80000
  const int E = in_sizes[1] / 2;        // 1280000
  const int CIN = in_sizes[0] / N;      // 128
  const int n_hid = in_sizes[5] / (64 * 64);  // 5

  const int* src = eidx;
  const int* dst = eidx + E;

  // workspace layout (256B-aligned slabs)
  char* ws = (char*)d_ws;
  size_t off = 0;
  auto alloc = [&](size_t bytes) {
    size_t o = off;
    off = (off + bytes + 255) & ~(size_t)255;
    return o;
  };
  int*            deg     = (int*)(ws + alloc((size_t)N * 4));
  int*            cursor  = (int*)(ws + alloc((size_t)N * 4));
  float*          dinv    = (float*)(ws + alloc((size_t)N * 4));
  int*            offs    = (int*)(ws + alloc((size_t)N * 4));
  int*            bsums   = (int*)(ws + alloc(1024 * 4));
  int*            csr_src = (int*)(ws + alloc((size_t)E * 4));
  unsigned short* tg      = (unsigned short*)(ws + alloc((size_t)N * 64 * 2));
  float*          hbuf    = (float*)(ws + alloc((size_t)N * 64 * 4));
  float*          gsum    = (float*)(ws + alloc(64 * 64 * 4));
  float*          gmax    = (float*)(ws + alloc(64 * 64 * 4));
  (void)ws_size; (void)n_in; (void)out_size; (void)CIN;

  const int nbN = (N + 255) / 256;   // 313

  init_kernel<<<nbN, 256, 0, stream>>>(deg, cursor, gsum, (unsigned int*)gmax, N);
  hist_kernel<<<1024, 256, 0, stream>>>(dst, deg, E, N);
  dinv_kernel<<<nbN, 256, 0, stream>>>(deg, dinv, N);
  scan1_kernel<<<nbN, 256, 0, stream>>>(deg, offs, bsums, N);
  scan2_kernel<<<1, 512, 0, stream>>>(bsums, nbN);
  scan3_kernel<<<nbN, 256, 0, stream>>>(offs, bsums, N);
  fill_kernel<<<1024, 256, 0, stream>>>(src, dst, offs, cursor, csr_src, E, N);

  const int ntiles = N >> 6;                    // 1250 (N % 64 == 0)
  const int agg_blocks = (N * 64 + 255) / 256;  // one wave per node

  // layer 0: 128 -> 64, ReLU
  gemm_kernel<128><<<ntiles, 256, 0, stream>>>(x, W_in, dinv, tg, N);
  agg_kernel<<<agg_blocks, 256, 0, stream>>>(tg, csr_src, offs, deg,
                                             dinv, b_in, hbuf, N, 1);
  // hidden layers: 64 -> 64, ReLU on all but last
  for (int i = 0; i < n_hid; ++i) {
    gemm_kernel<64><<<ntiles, 256, 0, stream>>>(hbuf, W_hid + (size_t)i * 64 * 64,
                                                dinv, tg, N);
    agg_kernel<<<agg_blocks, 256, 0, stream>>>(tg, csr_src, offs, deg,
                                               dinv, b_hid + (size_t)i * 64, hbuf, N,
                                               (i != n_hid - 1) ? 1 : 0);
  }

  const int pool_waves = (N + POOL_CHUNK - 1) / POOL_CHUNK;
  const int pool_blocks = (pool_waves * 64 + 255) / 256;
  pool_kernel<<<pool_blocks, 256, 0, stream>>>(hbuf, batch, gsum, gmax, N);

  mlp_kernel<<<1, 256, 0, stream>>>(gsum, gmax, lin1_w, lin1_b, lin2_w, lin2_b,
                                    lin3_w, lin3_b, out);
}